// Round 13
// baseline (693.782 us; speedup 1.0000x reference)
//
#include <hip/hip_runtime.h>
#include <hip/hip_bf16.h>

// Swin block: LN1+shift+window -> QKV GEMM -> [attention + proj + residual fused]
// -> LN2 -> fc1(+GELU) -> fc2(+residual), MLP as two qkv-class GEMMs.
//
// R13: mlp_fused (361us, stalls at 3.2x max-pipe; 6 probes exhausted) replaced
// by ln2_tok + 2x(gemm_fc1 -> gemm_fc2) over M-halves.  gemm_qkv's structure
// sustains ~570-600TF (R12 tail arithmetic) on the same tile shape; H-half bf16
// (134MB) + A_ln (67MB) exactly fill the dead qkv ws region.  fc1: K=256 N=1024,
// GELU in epilogue; fc2: K=1024 N=256, +fb2+x1 residual epilogue into d_out.
// All kernels before the MLP identical to R12 (633us best).

typedef __attribute__((ext_vector_type(8))) short bf16x8;
typedef __attribute__((ext_vector_type(4))) float f32x4;

#define QSCALE 0.17677669529663687f

__device__ __forceinline__ unsigned short f2bf(float f) {
  union { float f; unsigned u; } v; v.f = f;
  unsigned r = v.u + 0x7fffu + ((v.u >> 16) & 1u);
  return (unsigned short)(r >> 16);
}

__device__ __forceinline__ float gelu_f(float h) {
  const float t0 = h * h;
  const float y2 = h * fmaf(-0.0713548163f, t0, -1.5957691216f);
  const float e = __expf(y2);
  return h / (1.f + e);
}

__device__ __forceinline__ void gload_lds16(const unsigned short* g, void* l) {
  __builtin_amdgcn_global_load_lds(
      (const __attribute__((address_space(1))) unsigned int*)g,
      (__attribute__((address_space(3))) unsigned int*)l, 16, 0, 0);
}

// ---------------- all weight transpose-converts in one launch (786432 elems)
__global__ __launch_bounds__(256) void wt_all(const float* __restrict__ qw,
                                              const float* __restrict__ kvw,
                                              const float* __restrict__ projw,
                                              const float* __restrict__ fc1w,
                                              const float* __restrict__ fc2w,
                                              unsigned short* __restrict__ dst) {
  const int e = blockIdx.x * 256 + threadIdx.x;
  float v;
  if (e < 65536) {                                  // qw (scaled)
    const int n = e >> 8, k = e & 255;
    v = qw[k * 256 + n] * QSCALE;
  } else if (e < 196608) {                          // kvw
    const int l = e - 65536, n = l >> 8, k = l & 255;
    v = kvw[k * 512 + n];
  } else if (e < 262144) {                          // projw
    const int l = e - 196608, n = l >> 8, k = l & 255;
    v = projw[k * 256 + n];
  } else if (e < 524288) {                          // fc1w
    const int l = e - 262144, n = l >> 8, k = l & 255;
    v = fc1w[k * 1024 + n];
  } else {                                          // fc2w
    const int l = e - 524288, n = l >> 10, k = l & 1023;
    v = fc2w[k * 256 + n];
  }
  dst[e] = f2bf(v);
}

// ---------------- fused rel-pos bias + shift mask table: T[4][8][64][64] f32
__global__ __launch_bounds__(256) void bias_tab(const float* __restrict__ rpb,
                                                float* __restrict__ tab) {
  const int e = blockIdx.x * 256 + threadIdx.x;     // 131072 total
  const int type = e >> 15, rem = e & 32767;
  const int h = rem >> 12, nm = rem & 4095, n = nm >> 6, m = nm & 63;
  const int ni = n >> 3, nj = n & 7, mi = m >> 3, mj = m & 7;
  const float bias = rpb[((ni - mi + 7) * 15 + (nj - mj + 7)) * 8 + h];
  const int twi = type >> 1, twj = type & 1;
  const int rn = twi ? (ni < 4 ? 1 : 2) : 0;
  const int cn = twj ? (nj < 4 ? 1 : 2) : 0;
  const int rm_ = twi ? (mi < 4 ? 1 : 2) : 0;
  const int cm_ = twj ? (mj < 4 ? 1 : 2) : 0;
  tab[e] = bias + (((rn * 3 + cn) != (rm_ * 3 + cm_)) ? -100.f : 0.f);
}

// ---------------- LN1 + cyclic shift + window partition. One wave per token.
__global__ __launch_bounds__(256) void ln1_win(const float* __restrict__ x,
                                               const float* __restrict__ g,
                                               const float* __restrict__ b,
                                               unsigned short* __restrict__ hw) {
  const int wv = threadIdx.x >> 6, ln = threadIdx.x & 63;
  const int r = blockIdx.x * 4 + wv;           // window-order token
  const int bw = r >> 6, n = r & 63;
  const int bb = bw >> 8, wi = (bw >> 4) & 15, wj = bw & 15;
  const int sh = (wi * 8 + (n >> 3) + 4) & 127;
  const int sw = (wj * 8 + (n & 7) + 4) & 127;
  const long src = ((long)bb * 16384 + sh * 128 + sw) * 256;
  float4 v = *(const float4*)(x + src + ln * 4);
  float s = v.x + v.y + v.z + v.w;
  float q = v.x * v.x + v.y * v.y + v.z * v.z + v.w * v.w;
#pragma unroll
  for (int m = 1; m < 64; m <<= 1) { s += __shfl_xor(s, m); q += __shfl_xor(q, m); }
  const float mu = s * (1.f / 256.f);
  const float rstd = rsqrtf(q * (1.f / 256.f) - mu * mu + 1e-5f);
  const int c = ln * 4;
  ushort4 o;
  o.x = f2bf((v.x - mu) * rstd * g[c + 0] + b[c + 0]);
  o.y = f2bf((v.y - mu) * rstd * g[c + 1] + b[c + 1]);
  o.z = f2bf((v.z - mu) * rstd * g[c + 2] + b[c + 2]);
  o.w = f2bf((v.w - mu) * rstd * g[c + 3] + b[c + 3]);
  *(ushort4*)(hw + (long)r * 256 + c) = o;
}

// ---------------- LN2, token order (no shift). One wave per token.
__global__ __launch_bounds__(256) void ln2_tok(const float* __restrict__ x1,
                                               const float* __restrict__ g,
                                               const float* __restrict__ b,
                                               unsigned short* __restrict__ aln) {
  const int wv = threadIdx.x >> 6, ln = threadIdx.x & 63;
  const long r = (long)blockIdx.x * 4 + wv;
  float4 v = *(const float4*)(x1 + r * 256 + ln * 4);
  float s = v.x + v.y + v.z + v.w;
  float q = v.x * v.x + v.y * v.y + v.z * v.z + v.w * v.w;
#pragma unroll
  for (int m = 1; m < 64; m <<= 1) { s += __shfl_xor(s, m); q += __shfl_xor(q, m); }
  const float mu = s * (1.f / 256.f);
  const float rstd = rsqrtf(q * (1.f / 256.f) - mu * mu + 1e-5f);
  const int c = ln * 4;
  ushort4 o;
  o.x = f2bf((v.x - mu) * rstd * g[c + 0] + b[c + 0]);
  o.y = f2bf((v.y - mu) * rstd * g[c + 1] + b[c + 1]);
  o.z = f2bf((v.z - mu) * rstd * g[c + 2] + b[c + 2]);
  o.w = f2bf((v.w - mu) * rstd * g[c + 3] + b[c + 3]);
  *(ushort4*)(aln + r * 256 + c) = o;
}

// ---------------- QKV GEMM: [M=131072][K=256] x [N=768] -> qkv bf16  [R12]
__global__ __launch_bounds__(256) void gemm_qkv(const unsigned short* __restrict__ A,
                                                const unsigned short* __restrict__ Bt,
                                                const float* __restrict__ qb,
                                                const float* __restrict__ kvb,
                                                unsigned short* __restrict__ out) {
  __shared__ char lds[32768];
  char* la = lds; char* lb = lds + 16384;
  const int tid = threadIdx.x, wv = tid >> 6, ln = tid & 63;
  const int lid = blockIdx.y * 6 + blockIdx.x;     // linear dispatch id
  const int r8 = lid & 7, k6 = lid >> 3;           // XCD, 0..767
  const int tm = r8 * 128 + k6 / 6;                // 0..1023
  const int tn = k6 - 6 * (k6 / 6);                // 0..5
  const long a_base = (long)tm * 128 * 256;
  const long b_base = (long)tn * 128 * 256;
  const int wr = (wv >> 1) * 64, wc = (wv & 1) * 64;
  f32x4 acc[4][4] = {};
  for (int ks = 0; ks < 4; ++ks) {
    const int k0 = ks * 64;
    __syncthreads();
#pragma unroll
    for (int it = 0; it < 4; ++it) {
      int d = wv * 4096 + it * 1024 + ln * 16;
      int row = d >> 7;
      int seg = ((d >> 4) & 7) ^ (row & 7);        // pre-swizzled source (m173)
      gload_lds16(A + a_base + row * 256 + k0 + seg * 8, la + wv * 4096 + it * 1024);
      gload_lds16(Bt + b_base + row * 256 + k0 + seg * 8, lb + wv * 4096 + it * 1024);
    }
    __syncthreads();
#pragma unroll
    for (int kk = 0; kk < 2; ++kk) {
      bf16x8 af[4], bfr[4];
      const int kb = (kk * 32 + (ln >> 4) * 8) * 2;
#pragma unroll
      for (int i = 0; i < 4; ++i) {
        int ra = wr + i * 16 + (ln & 15);
        af[i] = *(const bf16x8*)(la + ra * 128 + (kb ^ ((ra & 7) << 4)));
        int rb = wc + i * 16 + (ln & 15);
        bfr[i] = *(const bf16x8*)(lb + rb * 128 + (kb ^ ((rb & 7) << 4)));
      }
#pragma unroll
      for (int i = 0; i < 4; ++i)
#pragma unroll
        for (int j = 0; j < 4; ++j)
          acc[i][j] = __builtin_amdgcn_mfma_f32_16x16x32_bf16(af[i], bfr[j], acc[i][j], 0, 0, 0);
    }
  }
#pragma unroll
  for (int j = 0; j < 4; ++j) {
    const int col = tn * 128 + wc + j * 16 + (ln & 15);
    const float bias = (col < 256) ? qb[col] * QSCALE : kvb[col - 256];
#pragma unroll
    for (int i = 0; i < 4; ++i) {
      const int r0 = tm * 128 + wr + i * 16 + (ln >> 4) * 4;
#pragma unroll
      for (int rg = 0; rg < 4; ++rg)
        out[(long)(r0 + rg) * 768 + col] = f2bf(acc[i][j][rg] + bias);
    }
  }
}

// ---------------- fc1 GEMM: [65536][256] x [1024] -> H bf16, GELU epilogue
// grid dim3(8, 512); XCD-bijective: 4096 = 8 XCD x 64 tm x 8 tn
__global__ __launch_bounds__(256) void gemm_fc1(const unsigned short* __restrict__ A,
                                                const unsigned short* __restrict__ Bt,
                                                const float* __restrict__ fb1,
                                                unsigned short* __restrict__ H) {
  __shared__ char lds[32768];
  char* la = lds; char* lb = lds + 16384;
  const int tid = threadIdx.x, wv = tid >> 6, ln = tid & 63;
  const int lid = blockIdx.y * 8 + blockIdx.x;
  const int r8 = lid & 7, k8 = lid >> 3;           // 0..511
  const int tm = r8 * 64 + (k8 >> 3);              // 0..511
  const int tn = k8 & 7;                           // 0..7
  const long a_base = (long)tm * 128 * 256;
  const long b_base = (long)tn * 128 * 256;
  const int wr = (wv >> 1) * 64, wc = (wv & 1) * 64;
  f32x4 acc[4][4] = {};
  for (int ks = 0; ks < 4; ++ks) {
    const int k0 = ks * 64;
    __syncthreads();
#pragma unroll
    for (int it = 0; it < 4; ++it) {
      int d = wv * 4096 + it * 1024 + ln * 16;
      int row = d >> 7;
      int seg = ((d >> 4) & 7) ^ (row & 7);
      gload_lds16(A + a_base + row * 256 + k0 + seg * 8, la + wv * 4096 + it * 1024);
      gload_lds16(Bt + b_base + row * 256 + k0 + seg * 8, lb + wv * 4096 + it * 1024);
    }
    __syncthreads();
#pragma unroll
    for (int kk = 0; kk < 2; ++kk) {
      bf16x8 af[4], bfr[4];
      const int kb = (kk * 32 + (ln >> 4) * 8) * 2;
#pragma unroll
      for (int i = 0; i < 4; ++i) {
        int ra = wr + i * 16 + (ln & 15);
        af[i] = *(const bf16x8*)(la + ra * 128 + (kb ^ ((ra & 7) << 4)));
        int rb = wc + i * 16 + (ln & 15);
        bfr[i] = *(const bf16x8*)(lb + rb * 128 + (kb ^ ((rb & 7) << 4)));
      }
#pragma unroll
      for (int i = 0; i < 4; ++i)
#pragma unroll
        for (int j = 0; j < 4; ++j)
          acc[i][j] = __builtin_amdgcn_mfma_f32_16x16x32_bf16(af[i], bfr[j], acc[i][j], 0, 0, 0);
    }
  }
#pragma unroll
  for (int j = 0; j < 4; ++j) {
    const int col = tn * 128 + wc + j * 16 + (ln & 15);
    const float fb = fb1[col];
#pragma unroll
    for (int i = 0; i < 4; ++i) {
      const int r0 = tm * 128 + wr + i * 16 + (ln >> 4) * 4;
#pragma unroll
      for (int rg = 0; rg < 4; ++rg)
        H[(long)(r0 + rg) * 1024 + col] = f2bf(gelu_f(acc[i][j][rg] + fb));
    }
  }
}

// ---------------- fc2 GEMM: [65536][1024] x [256] -> +fb2 +x1 residual -> out f32
// grid dim3(2, 512); XCD-bijective: 1024 = 8 XCD x 64 tm x 2 tn
__global__ __launch_bounds__(256) void gemm_fc2(const unsigned short* __restrict__ A,
                                                const unsigned short* __restrict__ Bt,
                                                const float* __restrict__ fb2,
                                                const float* __restrict__ x1,
                                                float* __restrict__ out,
                                                int mbase) {
  __shared__ char lds[32768];
  char* la = lds; char* lb = lds + 16384;
  const int tid = threadIdx.x, wv = tid >> 6, ln = tid & 63;
  const int lid = blockIdx.y * 2 + blockIdx.x;
  const int r8 = lid & 7, k2 = lid >> 3;           // 0..127
  const int tm = r8 * 64 + (k2 >> 1);              // 0..511
  const int tn = k2 & 1;                           // 0..1
  const long a_base = (long)tm * 128 * 1024;
  const long b_base = (long)tn * 128 * 1024;
  const int wr = (wv >> 1) * 64, wc = (wv & 1) * 64;
  f32x4 acc[4][4] = {};
  for (int ks = 0; ks < 16; ++ks) {
    const int k0 = ks * 64;
    __syncthreads();
#pragma unroll
    for (int it = 0; it < 4; ++it) {
      int d = wv * 4096 + it * 1024 + ln * 16;
      int row = d >> 7;
      int seg = ((d >> 4) & 7) ^ (row & 7);
      gload_lds16(A + a_base + row * 1024 + k0 + seg * 8, la + wv * 4096 + it * 1024);
      gload_lds16(Bt + b_base + row * 1024 + k0 + seg * 8, lb + wv * 4096 + it * 1024);
    }
    __syncthreads();
#pragma unroll
    for (int kk = 0; kk < 2; ++kk) {
      bf16x8 af[4], bfr[4];
      const int kb = (kk * 32 + (ln >> 4) * 8) * 2;
#pragma unroll
      for (int i = 0; i < 4; ++i) {
        int ra = wr + i * 16 + (ln & 15);
        af[i] = *(const bf16x8*)(la + ra * 128 + (kb ^ ((ra & 7) << 4)));
        int rb = wc + i * 16 + (ln & 15);
        bfr[i] = *(const bf16x8*)(lb + rb * 128 + (kb ^ ((rb & 7) << 4)));
      }
#pragma unroll
      for (int i = 0; i < 4; ++i)
#pragma unroll
        for (int j = 0; j < 4; ++j)
          acc[i][j] = __builtin_amdgcn_mfma_f32_16x16x32_bf16(af[i], bfr[j], acc[i][j], 0, 0, 0);
    }
  }
#pragma unroll
  for (int i = 0; i < 4; ++i) {
    const int r0 = tm * 128 + wr + i * 16 + (ln >> 4) * 4;
#pragma unroll
    for (int rg = 0; rg < 4; ++rg) {
      const long R = (long)mbase + r0 + rg;
#pragma unroll
      for (int j = 0; j < 4; ++j) {
        const int col = tn * 128 + wc + j * 16 + (ln & 15);
        out[R * 256 + col] = x1[R * 256 + col] + acc[i][j][rg] + fb2[col];
      }
    }
  }
}

// ---------------- fused attention + proj + window-reverse + residual  [R9]
__global__ __launch_bounds__(256, 2) void attn_proj(const unsigned short* __restrict__ qkv,
                                                    const float* __restrict__ tab,
                                                    const unsigned short* __restrict__ wp,
                                                    const float* __restrict__ pb,
                                                    const float* __restrict__ x,
                                                    float* __restrict__ x1) {
  __shared__ char lds[65536];
  const int tid = threadIdx.x, wv = tid >> 6, ln = tid & 63;
  const int bw = blockIdx.x;                 // window 0..2047
  char* vt = lds + wv * 16384;               // [64][64] u16, XOR swizzled
  char* pl = vt + 8192;                      // [64][64] bf16, XOR swizzled
  const long base = (long)bw * 64 * 768;
#pragma unroll
  for (int it = 0; it < 8; ++it) {
    bf16x8 v = *(const bf16x8*)(qkv + base + (long)ln * 768 + 512 + wv * 64 + it * 8);
#pragma unroll
    for (int u = 0; u < 8; ++u) {
      const int d = it * 8 + u;
      *(unsigned short*)(vt + ((d * 128 + 2 * ln) ^ ((d & 7) << 4))) = (unsigned short)v[u];
    }
  }
  const int wi = (bw >> 4) & 15, wj = bw & 15;
  const int type = ((wi == 15) ? 2 : 0) | ((wj == 15) ? 1 : 0);
  f32x4 oo[2][4][2];
#pragma unroll
  for (int hh = 0; hh < 2; ++hh) {
    const int h = wv * 2 + hh;
    const float* Tb = tab + (((type << 3) + h) << 12) + (ln & 15);
    f32x4 s[4][4] = {};
    {
      bf16x8 qf[4], kf[4];
      const int dk = (ln >> 4) * 8;
#pragma unroll
      for (int i = 0; i < 4; ++i) {
        const long rq = base + (long)(i * 16 + (ln & 15)) * 768;
        qf[i] = *(const bf16x8*)(qkv + rq + h * 32 + dk);
        kf[i] = *(const bf16x8*)(qkv + rq + 256 + h * 32 + dk);
      }
#pragma unroll
      for (int i = 0; i < 4; ++i)
#pragma unroll
        for (int j = 0; j < 4; ++j)
          s[i][j] = __builtin_amdgcn_mfma_f32_16x16x32_bf16(qf[i], kf[j], s[i][j], 0, 0, 0);
    }
#pragma unroll
    for (int i = 0; i < 4; ++i)
#pragma unroll
      for (int rg = 0; rg < 4; ++rg) {
        const int n = i * 16 + (ln >> 4) * 4 + rg;
        const float* Tn = Tb + n * 64;
#pragma unroll
        for (int j = 0; j < 4; ++j)
          s[i][j][rg] += Tn[j * 16];
      }
#pragma unroll
    for (int i = 0; i < 4; ++i)
#pragma unroll
      for (int rg = 0; rg < 4; ++rg) {
        float mx = fmaxf(fmaxf(s[i][0][rg], s[i][1][rg]), fmaxf(s[i][2][rg], s[i][3][rg]));
        mx = fmaxf(mx, __shfl_xor(mx, 1));
        mx = fmaxf(mx, __shfl_xor(mx, 2));
        mx = fmaxf(mx, __shfl_xor(mx, 4));
        mx = fmaxf(mx, __shfl_xor(mx, 8));
        float sum = 0.f;
#pragma unroll
        for (int j = 0; j < 4; ++j) { float e = __expf(s[i][j][rg] - mx); s[i][j][rg] = e; sum += e; }
        sum += __shfl_xor(sum, 1);
        sum += __shfl_xor(sum, 2);
        sum += __shfl_xor(sum, 4);
        sum += __shfl_xor(sum, 8);
        const float inv = 1.f / sum;
#pragma unroll
        for (int j = 0; j < 4; ++j) s[i][j][rg] *= inv;
      }
#pragma unroll
    for (int i = 0; i < 4; ++i)
#pragma unroll
      for (int rg = 0; rg < 4; ++rg) {
        const int n = i * 16 + (ln >> 4) * 4 + rg;
#pragma unroll
        for (int j = 0; j < 4; ++j) {
          const int m = j * 16 + (ln & 15);
          *(unsigned short*)(pl + n * 128 + ((m * 2) ^ ((n & 7) << 4))) = f2bf(s[i][j][rg]);
        }
      }
#pragma unroll
    for (int i = 0; i < 4; ++i)
#pragma unroll
      for (int j = 0; j < 2; ++j) oo[hh][i][j] = (f32x4){0.f, 0.f, 0.f, 0.f};
#pragma unroll
    for (int kk = 0; kk < 2; ++kk) {
      const int km = kk * 32 + (ln >> 4) * 8;
      bf16x8 pa[4], vb[2];
#pragma unroll
      for (int i = 0; i < 4; ++i) {
        const int n = i * 16 + (ln & 15);
        pa[i] = *(const bf16x8*)(pl + n * 128 + ((km * 2) ^ ((n & 7) << 4)));
      }
#pragma unroll
      for (int j = 0; j < 2; ++j) {
        const int r = hh * 32 + j * 16 + (ln & 15);
        vb[j] = *(const bf16x8*)(vt + ((r * 128 + km * 2) ^ ((r & 7) << 4)));
      }
#pragma unroll
      for (int i = 0; i < 4; ++i)
#pragma unroll
        for (int j = 0; j < 2; ++j)
          oo[hh][i][j] = __builtin_amdgcn_mfma_f32_16x16x32_bf16(pa[i], vb[j], oo[hh][i][j], 0, 0, 0);
    }
  }
  __syncthreads();                 // all waves done with vt/pl
#pragma unroll
  for (int hh = 0; hh < 2; ++hh)
#pragma unroll
    for (int i = 0; i < 4; ++i)
#pragma unroll
      for (int j = 0; j < 2; ++j)
#pragma unroll
        for (int rg = 0; rg < 4; ++rg) {
          const int t = i * 16 + (ln >> 4) * 4 + rg;
          const int c = wv * 64 + hh * 32 + j * 16 + (ln & 15);
          *(unsigned short*)(lds + t * 512 + ((c * 2) ^ ((t & 7) << 4))) = f2bf(oo[hh][i][j][rg]);
        }
  __syncthreads();                 // O ready
  f32x4 acc[4][4] = {};
#pragma unroll
  for (int kk = 0; kk < 8; ++kk) {
    bf16x8 af[4], bfr[4];
    const int kb = (kk * 32 + (ln >> 4) * 8) * 2;
#pragma unroll
    for (int i = 0; i < 4; ++i) {
      const int ra = i * 16 + (ln & 15);
      af[i] = *(const bf16x8*)(lds + ra * 512 + (kb ^ ((ra & 7) << 4)));
    }
#pragma unroll
    for (int j = 0; j < 4; ++j)
      bfr[j] = *(const bf16x8*)(wp + (long)(wv * 64 + j * 16 + (ln & 15)) * 256 +
                                kk * 32 + (ln >> 4) * 8);
#pragma unroll
    for (int i = 0; i < 4; ++i)
#pragma unroll
      for (int j = 0; j < 4; ++j)
        acc[i][j] = __builtin_amdgcn_mfma_f32_16x16x32_bf16(af[i], bfr[j], acc[i][j], 0, 0, 0);
  }
  const int bb = bw >> 8;
#pragma unroll
  for (int i = 0; i < 4; ++i)
#pragma unroll
    for (int rg = 0; rg < 4; ++rg) {
      const int n = i * 16 + (ln >> 4) * 4 + rg;
      const int sh = (wi * 8 + (n >> 3) + 4) & 127;
      const int sw = (wj * 8 + (n & 7) + 4) & 127;
      const long dst = ((long)bb * 16384 + sh * 128 + sw) * 256;
#pragma unroll
      for (int j = 0; j < 4; ++j) {
        const int col = wv * 64 + j * 16 + (ln & 15);
        x1[dst + col] = x[dst + col] + acc[i][j][rg] + pb[col];
      }
    }
}

extern "C" void kernel_launch(void* const* d_in, const int* in_sizes, int n_in,
                              void* d_out, int out_size, void* d_ws, size_t ws_size,
                              hipStream_t stream) {
  const float* x     = (const float*)d_in[0];
  const float* g1    = (const float*)d_in[1];
  const float* b1    = (const float*)d_in[2];
  const float* qw    = (const float*)d_in[3];
  const float* qb    = (const float*)d_in[4];
  const float* kvw   = (const float*)d_in[5];
  const float* kvb   = (const float*)d_in[6];
  const float* rpb   = (const float*)d_in[7];
  const float* projw = (const float*)d_in[8];
  const float* projb = (const float*)d_in[9];
  const float* g2    = (const float*)d_in[10];
  const float* b2    = (const float*)d_in[11];
  const float* fc1w  = (const float*)d_in[12];
  const float* fc1b  = (const float*)d_in[13];
  const float* fc2w  = (const float*)d_in[14];
  const float* fc2b  = (const float*)d_in[15];

  // Workspace: weights bf16 | qkv bf16 (reused: A_ln 33.5M + H-half 67M u16)
  // | tab f32   (~194 MB)
  unsigned short* wqkv  = (unsigned short*)d_ws;            // 196608
  unsigned short* wproj = wqkv + 196608;                     // 65536
  unsigned short* wfc1  = wproj + 65536;                     // 262144
  unsigned short* wfc2  = wfc1 + 262144;                     // 262144
  unsigned short* qkv   = wfc2 + 262144;                     // 100663296
  unsigned short* aln   = qkv;                               // [131072][256] bf16
  unsigned short* Hbuf  = qkv + 33554432;                    // [65536][1024] bf16
  float* tab = (float*)(qkv + 100663296);                    // 131072 f32
  // d_out f32: ln1's hw bf16 scratch in first half (dead after gemm_qkv);
  // attn_proj writes x1 f32 over d_out; fc2 rewrites d_out in place.
  unsigned short* hw = (unsigned short*)d_out;
  float* x1 = (float*)d_out;

  wt_all<<<3072, 256, 0, stream>>>(qw, kvw, projw, fc1w, fc2w, wqkv);
  bias_tab<<<512, 256, 0, stream>>>(rpb, tab);

  ln1_win<<<32768, 256, 0, stream>>>(x, g1, b1, hw);
  gemm_qkv<<<dim3(6, 1024), 256, 0, stream>>>(hw, wqkv, qb, kvb, qkv);
  attn_proj<<<2048, 256, 0, stream>>>(qkv, tab, wproj, projb, x, x1);
  // MLP as split GEMMs: LN2 -> (fc1 -> fc2) per 65536-token half
  ln2_tok<<<32768, 256, 0, stream>>>(x1, g2, b2, aln);
  gemm_fc1<<<dim3(8, 512), 256, 0, stream>>>(aln, wfc1, fc1b, Hbuf);
  gemm_fc2<<<dim3(2, 512), 256, 0, stream>>>(Hbuf, wfc2, fc2b, x1, (float*)d_out, 0);
  gemm_fc1<<<dim3(8, 512), 256, 0, stream>>>(aln + (long)65536 * 256, wfc1, fc1b, Hbuf);
  gemm_fc2<<<dim3(2, 512), 256, 0, stream>>>(Hbuf, wfc2, fc2b, x1, (float*)d_out, 65536);
}

// Round 14
// 633.761 us; speedup vs baseline: 1.0947x; 1.0947x over previous
//
#include <hip/hip_runtime.h>
#include <hip/hip_bf16.h>

// Swin block: LN1+shift+window -> QKV GEMM -> [attention + proj + residual fused]
// -> LN2+MLP(GELU)+residual fused.  bf16 MFMA 16x16x32, f32 accum.
//
// R14: revert to R12 (633us best; R13's split MLP ran at the SAME ~380TF
// structure rate but added ln2 + H round-trip -> 694us).  One bounded change:
// attn_proj stages V per-head (vt [32][64] = 4KB/wave, restaged inside the hh
// loop, wave-private) -> per-wave LDS 16->12KB, block 64->48KB -> 3 blocks/CU
// possible.  launch_bounds stays (256,2) (floor; avoids R10's VGPR-84 spill).
// Worst case neutral (same op counts), best case +50% occupancy on the
// latency-bound attn_proj (177us, occ 20.7%, no pipe >24%).

typedef __attribute__((ext_vector_type(8))) short bf16x8;
typedef __attribute__((ext_vector_type(4))) float f32x4;

#define QSCALE 0.17677669529663687f

__device__ __forceinline__ unsigned short f2bf(float f) {
  union { float f; unsigned u; } v; v.f = f;
  unsigned r = v.u + 0x7fffu + ((v.u >> 16) & 1u);
  return (unsigned short)(r >> 16);
}

__device__ __forceinline__ float gelu_f(float h) {
  const float t0 = h * h;
  const float y2 = h * fmaf(-0.0713548163f, t0, -1.5957691216f);
  const float e = __expf(y2);
  return h / (1.f + e);
}

__device__ __forceinline__ void gload_lds16(const unsigned short* g, void* l) {
  __builtin_amdgcn_global_load_lds(
      (const __attribute__((address_space(1))) unsigned int*)g,
      (__attribute__((address_space(3))) unsigned int*)l, 16, 0, 0);
}

// ---------------- all weight transpose-converts in one launch (786432 elems)
__global__ __launch_bounds__(256) void wt_all(const float* __restrict__ qw,
                                              const float* __restrict__ kvw,
                                              const float* __restrict__ projw,
                                              const float* __restrict__ fc1w,
                                              const float* __restrict__ fc2w,
                                              unsigned short* __restrict__ dst) {
  const int e = blockIdx.x * 256 + threadIdx.x;
  float v;
  if (e < 65536) {                                  // qw (scaled)
    const int n = e >> 8, k = e & 255;
    v = qw[k * 256 + n] * QSCALE;
  } else if (e < 196608) {                          // kvw
    const int l = e - 65536, n = l >> 8, k = l & 255;
    v = kvw[k * 512 + n];
  } else if (e < 262144) {                          // projw
    const int l = e - 196608, n = l >> 8, k = l & 255;
    v = projw[k * 256 + n];
  } else if (e < 524288) {                          // fc1w
    const int l = e - 262144, n = l >> 8, k = l & 255;
    v = fc1w[k * 1024 + n];
  } else {                                          // fc2w
    const int l = e - 524288, n = l >> 10, k = l & 1023;
    v = fc2w[k * 256 + n];
  }
  dst[e] = f2bf(v);
}

// ---------------- fused rel-pos bias + shift mask table: T[4][8][64][64] f32
__global__ __launch_bounds__(256) void bias_tab(const float* __restrict__ rpb,
                                                float* __restrict__ tab) {
  const int e = blockIdx.x * 256 + threadIdx.x;     // 131072 total
  const int type = e >> 15, rem = e & 32767;
  const int h = rem >> 12, nm = rem & 4095, n = nm >> 6, m = nm & 63;
  const int ni = n >> 3, nj = n & 7, mi = m >> 3, mj = m & 7;
  const float bias = rpb[((ni - mi + 7) * 15 + (nj - mj + 7)) * 8 + h];
  const int twi = type >> 1, twj = type & 1;
  const int rn = twi ? (ni < 4 ? 1 : 2) : 0;
  const int cn = twj ? (nj < 4 ? 1 : 2) : 0;
  const int rm_ = twi ? (mi < 4 ? 1 : 2) : 0;
  const int cm_ = twj ? (mj < 4 ? 1 : 2) : 0;
  tab[e] = bias + (((rn * 3 + cn) != (rm_ * 3 + cm_)) ? -100.f : 0.f);
}

// ---------------- LN1 + cyclic shift + window partition. One wave per token.
__global__ __launch_bounds__(256) void ln1_win(const float* __restrict__ x,
                                               const float* __restrict__ g,
                                               const float* __restrict__ b,
                                               unsigned short* __restrict__ hw) {
  const int wv = threadIdx.x >> 6, ln = threadIdx.x & 63;
  const int r = blockIdx.x * 4 + wv;           // window-order token
  const int bw = r >> 6, n = r & 63;
  const int bb = bw >> 8, wi = (bw >> 4) & 15, wj = bw & 15;
  const int sh = (wi * 8 + (n >> 3) + 4) & 127;
  const int sw = (wj * 8 + (n & 7) + 4) & 127;
  const long src = ((long)bb * 16384 + sh * 128 + sw) * 256;
  float4 v = *(const float4*)(x + src + ln * 4);
  float s = v.x + v.y + v.z + v.w;
  float q = v.x * v.x + v.y * v.y + v.z * v.z + v.w * v.w;
#pragma unroll
  for (int m = 1; m < 64; m <<= 1) { s += __shfl_xor(s, m); q += __shfl_xor(q, m); }
  const float mu = s * (1.f / 256.f);
  const float rstd = rsqrtf(q * (1.f / 256.f) - mu * mu + 1e-5f);
  const int c = ln * 4;
  ushort4 o;
  o.x = f2bf((v.x - mu) * rstd * g[c + 0] + b[c + 0]);
  o.y = f2bf((v.y - mu) * rstd * g[c + 1] + b[c + 1]);
  o.z = f2bf((v.z - mu) * rstd * g[c + 2] + b[c + 2]);
  o.w = f2bf((v.w - mu) * rstd * g[c + 3] + b[c + 3]);
  *(ushort4*)(hw + (long)r * 256 + c) = o;
}

// ---------------- QKV GEMM: [M=131072][K=256] x [N=768] -> qkv bf16  [R12]
__global__ __launch_bounds__(256) void gemm_qkv(const unsigned short* __restrict__ A,
                                                const unsigned short* __restrict__ Bt,
                                                const float* __restrict__ qb,
                                                const float* __restrict__ kvb,
                                                unsigned short* __restrict__ out) {
  __shared__ char lds[32768];
  char* la = lds; char* lb = lds + 16384;
  const int tid = threadIdx.x, wv = tid >> 6, ln = tid & 63;
  const int lid = blockIdx.y * 6 + blockIdx.x;     // linear dispatch id
  const int r8 = lid & 7, k6 = lid >> 3;           // XCD, 0..767
  const int tm = r8 * 128 + k6 / 6;                // 0..1023
  const int tn = k6 - 6 * (k6 / 6);                // 0..5
  const long a_base = (long)tm * 128 * 256;
  const long b_base = (long)tn * 128 * 256;
  const int wr = (wv >> 1) * 64, wc = (wv & 1) * 64;
  f32x4 acc[4][4] = {};
  for (int ks = 0; ks < 4; ++ks) {
    const int k0 = ks * 64;
    __syncthreads();
#pragma unroll
    for (int it = 0; it < 4; ++it) {
      int d = wv * 4096 + it * 1024 + ln * 16;
      int row = d >> 7;
      int seg = ((d >> 4) & 7) ^ (row & 7);        // pre-swizzled source (m173)
      gload_lds16(A + a_base + row * 256 + k0 + seg * 8, la + wv * 4096 + it * 1024);
      gload_lds16(Bt + b_base + row * 256 + k0 + seg * 8, lb + wv * 4096 + it * 1024);
    }
    __syncthreads();
#pragma unroll
    for (int kk = 0; kk < 2; ++kk) {
      bf16x8 af[4], bfr[4];
      const int kb = (kk * 32 + (ln >> 4) * 8) * 2;
#pragma unroll
      for (int i = 0; i < 4; ++i) {
        int ra = wr + i * 16 + (ln & 15);
        af[i] = *(const bf16x8*)(la + ra * 128 + (kb ^ ((ra & 7) << 4)));
        int rb = wc + i * 16 + (ln & 15);
        bfr[i] = *(const bf16x8*)(lb + rb * 128 + (kb ^ ((rb & 7) << 4)));
      }
#pragma unroll
      for (int i = 0; i < 4; ++i)
#pragma unroll
        for (int j = 0; j < 4; ++j)
          acc[i][j] = __builtin_amdgcn_mfma_f32_16x16x32_bf16(af[i], bfr[j], acc[i][j], 0, 0, 0);
    }
  }
#pragma unroll
  for (int j = 0; j < 4; ++j) {
    const int col = tn * 128 + wc + j * 16 + (ln & 15);
    const float bias = (col < 256) ? qb[col] * QSCALE : kvb[col - 256];
#pragma unroll
    for (int i = 0; i < 4; ++i) {
      const int r0 = tm * 128 + wr + i * 16 + (ln >> 4) * 4;
#pragma unroll
      for (int rg = 0; rg < 4; ++rg)
        out[(long)(r0 + rg) * 768 + col] = f2bf(acc[i][j][rg] + bias);
    }
  }
}

// ---------------- fused attention + proj + window-reverse + residual
// R14: per-wave LDS 12KB (vt [32][64] u16 per-head, restaged per hh; pl 8KB)
// -> block 48KB -> up to 3 blocks/CU.  Otherwise identical to R9/R12.
__global__ __launch_bounds__(256, 2) void attn_proj(const unsigned short* __restrict__ qkv,
                                                    const float* __restrict__ tab,
                                                    const unsigned short* __restrict__ wp,
                                                    const float* __restrict__ pb,
                                                    const float* __restrict__ x,
                                                    float* __restrict__ x1) {
  __shared__ char lds[49152];
  const int tid = threadIdx.x, wv = tid >> 6, ln = tid & 63;
  const int bw = blockIdx.x;                 // window 0..2047
  char* vt = lds + wv * 12288;               // [32][64] u16, XOR swizzled (4KB)
  char* pl = vt + 4096;                      // [64][64] bf16, XOR swizzled (8KB)
  const long base = (long)bw * 64 * 768;
  const int wi = (bw >> 4) & 15, wj = bw & 15;
  const int type = ((wi == 15) ? 2 : 0) | ((wj == 15) ? 1 : 0);
  f32x4 oo[2][4][2];
#pragma unroll
  for (int hh = 0; hh < 2; ++hh) {
    const int h = wv * 2 + hh;
    // stage this head's V (32 cols) transposed into vt (wave-private, no barrier)
#pragma unroll
    for (int it = 0; it < 4; ++it) {
      bf16x8 v = *(const bf16x8*)(qkv + base + (long)ln * 768 + 512 + h * 32 + it * 8);
#pragma unroll
      for (int u = 0; u < 8; ++u) {
        const int d = it * 8 + u;
        *(unsigned short*)(vt + ((d * 128 + 2 * ln) ^ ((d & 7) << 4))) = (unsigned short)v[u];
      }
    }
    const float* Tb = tab + (((type << 3) + h) << 12) + (ln & 15);
    f32x4 s[4][4] = {};
    {
      bf16x8 qf[4], kf[4];
      const int dk = (ln >> 4) * 8;
#pragma unroll
      for (int i = 0; i < 4; ++i) {
        const long rq = base + (long)(i * 16 + (ln & 15)) * 768;
        qf[i] = *(const bf16x8*)(qkv + rq + h * 32 + dk);
        kf[i] = *(const bf16x8*)(qkv + rq + 256 + h * 32 + dk);
      }
#pragma unroll
      for (int i = 0; i < 4; ++i)
#pragma unroll
        for (int j = 0; j < 4; ++j)
          s[i][j] = __builtin_amdgcn_mfma_f32_16x16x32_bf16(qf[i], kf[j], s[i][j], 0, 0, 0);
    }
#pragma unroll
    for (int i = 0; i < 4; ++i)
#pragma unroll
      for (int rg = 0; rg < 4; ++rg) {
        const int n = i * 16 + (ln >> 4) * 4 + rg;
        const float* Tn = Tb + n * 64;
#pragma unroll
        for (int j = 0; j < 4; ++j)
          s[i][j][rg] += Tn[j * 16];
      }
#pragma unroll
    for (int i = 0; i < 4; ++i)
#pragma unroll
      for (int rg = 0; rg < 4; ++rg) {
        float mx = fmaxf(fmaxf(s[i][0][rg], s[i][1][rg]), fmaxf(s[i][2][rg], s[i][3][rg]));
        mx = fmaxf(mx, __shfl_xor(mx, 1));
        mx = fmaxf(mx, __shfl_xor(mx, 2));
        mx = fmaxf(mx, __shfl_xor(mx, 4));
        mx = fmaxf(mx, __shfl_xor(mx, 8));
        float sum = 0.f;
#pragma unroll
        for (int j = 0; j < 4; ++j) { float e = __expf(s[i][j][rg] - mx); s[i][j][rg] = e; sum += e; }
        sum += __shfl_xor(sum, 1);
        sum += __shfl_xor(sum, 2);
        sum += __shfl_xor(sum, 4);
        sum += __shfl_xor(sum, 8);
        const float inv = 1.f / sum;
#pragma unroll
        for (int j = 0; j < 4; ++j) s[i][j][rg] *= inv;
      }
#pragma unroll
    for (int i = 0; i < 4; ++i)
#pragma unroll
      for (int rg = 0; rg < 4; ++rg) {
        const int n = i * 16 + (ln >> 4) * 4 + rg;
#pragma unroll
        for (int j = 0; j < 4; ++j) {
          const int m = j * 16 + (ln & 15);
          *(unsigned short*)(pl + n * 128 + ((m * 2) ^ ((n & 7) << 4))) = f2bf(s[i][j][rg]);
        }
      }
#pragma unroll
    for (int i = 0; i < 4; ++i)
#pragma unroll
      for (int j = 0; j < 2; ++j) oo[hh][i][j] = (f32x4){0.f, 0.f, 0.f, 0.f};
#pragma unroll
    for (int kk = 0; kk < 2; ++kk) {
      const int km = kk * 32 + (ln >> 4) * 8;
      bf16x8 pa[4], vb[2];
#pragma unroll
      for (int i = 0; i < 4; ++i) {
        const int n = i * 16 + (ln & 15);
        pa[i] = *(const bf16x8*)(pl + n * 128 + ((km * 2) ^ ((n & 7) << 4)));
      }
#pragma unroll
      for (int j = 0; j < 2; ++j) {
        const int r = j * 16 + (ln & 15);            // d within head (0..31)
        vb[j] = *(const bf16x8*)(vt + ((r * 128 + km * 2) ^ ((r & 7) << 4)));
      }
#pragma unroll
      for (int i = 0; i < 4; ++i)
#pragma unroll
        for (int j = 0; j < 2; ++j)
          oo[hh][i][j] = __builtin_amdgcn_mfma_f32_16x16x32_bf16(pa[i], vb[j], oo[hh][i][j], 0, 0, 0);
    }
  }
  __syncthreads();                 // all waves done with vt/pl
  // ---- O [64][256] bf16 swizzled into lds[0..32767]
#pragma unroll
  for (int hh = 0; hh < 2; ++hh)
#pragma unroll
    for (int i = 0; i < 4; ++i)
#pragma unroll
      for (int j = 0; j < 2; ++j)
#pragma unroll
        for (int rg = 0; rg < 4; ++rg) {
          const int t = i * 16 + (ln >> 4) * 4 + rg;
          const int c = wv * 64 + hh * 32 + j * 16 + (ln & 15);
          *(unsigned short*)(lds + t * 512 + ((c * 2) ^ ((t & 7) << 4))) = f2bf(oo[hh][i][j][rg]);
        }
  __syncthreads();                 // O ready
  f32x4 acc[4][4] = {};
#pragma unroll
  for (int kk = 0; kk < 8; ++kk) {
    bf16x8 af[4], bfr[4];
    const int kb = (kk * 32 + (ln >> 4) * 8) * 2;
#pragma unroll
    for (int i = 0; i < 4; ++i) {
      const int ra = i * 16 + (ln & 15);
      af[i] = *(const bf16x8*)(lds + ra * 512 + (kb ^ ((ra & 7) << 4)));
    }
#pragma unroll
    for (int j = 0; j < 4; ++j)
      bfr[j] = *(const bf16x8*)(wp + (long)(wv * 64 + j * 16 + (ln & 15)) * 256 +
                                kk * 32 + (ln >> 4) * 8);
#pragma unroll
    for (int i = 0; i < 4; ++i)
#pragma unroll
      for (int j = 0; j < 4; ++j)
        acc[i][j] = __builtin_amdgcn_mfma_f32_16x16x32_bf16(af[i], bfr[j], acc[i][j], 0, 0, 0);
  }
  const int bb = bw >> 8;
#pragma unroll
  for (int i = 0; i < 4; ++i)
#pragma unroll
    for (int rg = 0; rg < 4; ++rg) {
      const int n = i * 16 + (ln >> 4) * 4 + rg;
      const int sh = (wi * 8 + (n >> 3) + 4) & 127;
      const int sw = (wj * 8 + (n & 7) + 4) & 127;
      const long dst = ((long)bb * 16384 + sh * 128 + sw) * 256;
#pragma unroll
      for (int j = 0; j < 4; ++j) {
        const int col = wv * 64 + j * 16 + (ln & 15);
        x1[dst + col] = x[dst + col] + acc[i][j][rg] + pb[col];
      }
    }
}

// ---------------- fused LN2 + fc1 + GELU + fc2 + residual (f32 out)  [R9/R5]
__global__ __launch_bounds__(256, 2) void mlp_fused(const float* __restrict__ x1,
                                                    const float* __restrict__ g2,
                                                    const float* __restrict__ b2,
                                                    const unsigned short* __restrict__ w1t,
                                                    const float* __restrict__ fb1,
                                                    const unsigned short* __restrict__ w2t,
                                                    const float* __restrict__ fb2,
                                                    float* __restrict__ out) {
  __shared__ char lds[65536];           // A_ln 32KB | H0 16KB | H1 16KB
  char* h0 = lds + 32768;
  char* h1 = lds + 49152;
  const int tid = threadIdx.x, wv = tid >> 6, ln = tid & 63;
  const long rbase = (long)blockIdx.x * 64;
  {
    const int t = tid >> 2, q = tid & 3;
    const float* xr = x1 + (rbase + t) * 256 + q * 64;
    float4 v[16];
    float s = 0.f, sq = 0.f;
#pragma unroll
    for (int u = 0; u < 16; ++u) {
      v[u] = *(const float4*)(xr + u * 4);
      s += v[u].x + v[u].y + v[u].z + v[u].w;
      sq += v[u].x * v[u].x + v[u].y * v[u].y + v[u].z * v[u].z + v[u].w * v[u].w;
    }
    s += __shfl_xor(s, 1); s += __shfl_xor(s, 2);
    sq += __shfl_xor(sq, 1); sq += __shfl_xor(sq, 2);
    const float mu = s * (1.f / 256.f);
    const float rstd = rsqrtf(sq * (1.f / 256.f) - mu * mu + 1e-5f);
#pragma unroll
    for (int c8 = 0; c8 < 8; ++c8) {
      bf16x8 o;
#pragma unroll
      for (int u = 0; u < 8; ++u) {
        const int col = q * 64 + c8 * 8 + u;
        const float fv = ((&v[c8 * 2 + (u >> 2)].x)[u & 3] - mu) * rstd * g2[col] + b2[col];
        o[u] = (short)f2bf(fv);
      }
      *(bf16x8*)(lds + t * 512 + (((q * 64 + c8 * 8) * 2) ^ ((t & 7) << 4))) = o;
    }
  }

  f32x4 acc[4][4] = {};
  f32x4 hc[4][2];

  auto fc1_compute = [&](int ch) {
#pragma unroll
    for (int i = 0; i < 4; ++i)
#pragma unroll
      for (int j = 0; j < 2; ++j) hc[i][j] = (f32x4){0.f, 0.f, 0.f, 0.f};
#pragma unroll
    for (int ks = 0; ks < 8; ++ks) {
      bf16x8 af[4], wf[2];
#pragma unroll
      for (int j = 0; j < 2; ++j)
        wf[j] = *(const bf16x8*)(w1t + (long)(ch * 128 + wv * 32 + j * 16 + (ln & 15)) * 256 +
                                 ks * 32 + (ln >> 4) * 8);
      const int kb = (ks * 32 + (ln >> 4) * 8) * 2;
#pragma unroll
      for (int i = 0; i < 4; ++i) {
        const int ra = i * 16 + (ln & 15);
        af[i] = *(const bf16x8*)(lds + ra * 512 + (kb ^ ((ra & 7) << 4)));
      }
#pragma unroll
      for (int i = 0; i < 4; ++i)
#pragma unroll
        for (int j = 0; j < 2; ++j)
          hc[i][j] = __builtin_amdgcn_mfma_f32_16x16x32_bf16(af[i], wf[j], hc[i][j], 0, 0, 0);
    }
  };

  auto gelu_store = [&](int ch, char* hdst) {
#pragma unroll
    for (int j = 0; j < 2; ++j) {
      const int cH = wv * 32 + j * 16 + (ln & 15);
      const float fb = fb1[ch * 128 + cH];
#pragma unroll
      for (int i = 0; i < 4; ++i)
#pragma unroll
        for (int rg = 0; rg < 4; ++rg) {
          const int t = i * 16 + (ln >> 4) * 4 + rg;
          const float val = hc[i][j][rg] + fb;
          *(unsigned short*)(hdst + t * 256 + ((cH * 2) ^ ((t & 7) << 4))) = f2bf(gelu_f(val));
        }
    }
  };

  auto fc2_compute = [&](int ch, const char* hsrc) {
#pragma unroll
    for (int kk = 0; kk < 4; ++kk) {
      const int kb2 = kk * 32 + (ln >> 4) * 8;
      bf16x8 ha[4], wb[4];
#pragma unroll
      for (int j = 0; j < 4; ++j)
        wb[j] = *(const bf16x8*)(w2t + (long)(wv * 64 + j * 16 + (ln & 15)) * 1024 +
                                 ch * 128 + kb2);
#pragma unroll
      for (int i = 0; i < 4; ++i) {
        const int tt = i * 16 + (ln & 15);
        ha[i] = *(const bf16x8*)(hsrc + tt * 256 + ((kb2 * 2) ^ ((tt & 7) << 4)));
      }
#pragma unroll
      for (int i = 0; i < 4; ++i)
#pragma unroll
        for (int j = 0; j < 4; ++j)
          acc[i][j] = __builtin_amdgcn_mfma_f32_16x16x32_bf16(ha[i], wb[j], acc[i][j], 0, 0, 0);
    }
  };

  __syncthreads();              // A_ln ready
  fc1_compute(0);
  gelu_store(0, h0);
  __syncthreads();              // H0 ready
#pragma unroll 2
  for (int ch = 0; ch < 8; ++ch) {
    char* hr = (ch & 1) ? h1 : h0;
    char* hw2 = (ch & 1) ? h0 : h1;
    if (ch < 7) fc1_compute(ch + 1);   // indep chain: W1 global + A LDS
    fc2_compute(ch, hr);               // indep chain: H LDS + W2 global
    if (ch < 7) {
      gelu_store(ch + 1, hw2);
      __syncthreads();                 // H[(ch+1)&1] ready; H[ch&1] free
    }
  }
#pragma unroll
  for (int i = 0; i < 4; ++i)
#pragma unroll
    for (int rg = 0; rg < 4; ++rg) {
      const long t = rbase + i * 16 + (ln >> 4) * 4 + rg;
#pragma unroll
      for (int j = 0; j < 4; ++j) {
        const int col = wv * 64 + j * 16 + (ln & 15);
        out[t * 256 + col] = x1[t * 256 + col] + acc[i][j][rg] + fb2[col];
      }
    }
}

extern "C" void kernel_launch(void* const* d_in, const int* in_sizes, int n_in,
                              void* d_out, int out_size, void* d_ws, size_t ws_size,
                              hipStream_t stream) {
  const float* x     = (const float*)d_in[0];
  const float* g1    = (const float*)d_in[1];
  const float* b1    = (const float*)d_in[2];
  const float* qw    = (const float*)d_in[3];
  const float* qb    = (const float*)d_in[4];
  const float* kvw   = (const float*)d_in[5];
  const float* kvb   = (const float*)d_in[6];
  const float* rpb   = (const float*)d_in[7];
  const float* projw = (const float*)d_in[8];
  const float* projb = (const float*)d_in[9];
  const float* g2    = (const float*)d_in[10];
  const float* b2    = (const float*)d_in[11];
  const float* fc1w  = (const float*)d_in[12];
  const float* fc1b  = (const float*)d_in[13];
  const float* fc2w  = (const float*)d_in[14];
  const float* fc2b  = (const float*)d_in[15];

  // Workspace: weights bf16 | qkv bf16 | tab f32   (~203.4 MB)
  unsigned short* wqkv  = (unsigned short*)d_ws;            // 196608
  unsigned short* wproj = wqkv + 196608;                     // 65536
  unsigned short* wfc1  = wproj + 65536;                     // 262144
  unsigned short* wfc2  = wfc1 + 262144;                     // 262144
  unsigned short* qkv   = wfc2 + 262144;                     // 100663296
  float* tab = (float*)(qkv + 100663296);                    // 131072 f32
  // d_out f32: ln1's hw bf16 scratch in first half (dead after gemm_qkv);
  // attn_proj writes x1 f32 over d_out; mlp_fused rewrites in place.
  unsigned short* hw = (unsigned short*)d_out;
  float* x1 = (float*)d_out;

  wt_all<<<3072, 256, 0, stream>>>(qw, kvw, projw, fc1w, fc2w, wqkv);
  bias_tab<<<512, 256, 0, stream>>>(rpb, tab);

  ln1_win<<<32768, 256, 0, stream>>>(x, g1, b1, hw);
  gemm_qkv<<<dim3(6, 1024), 256, 0, stream>>>(hw, wqkv, qb, kvb, qkv);
  attn_proj<<<2048, 256, 0, stream>>>(qkv, tab, wproj, projb, x, x1);
  mlp_fused<<<2048, 256, 0, stream>>>(x1, g2, b2, wfc1, fc1b, wfc2, fc2b,
                                      (float*)d_out);
}

// Round 15
// 624.860 us; speedup vs baseline: 1.1103x; 1.0142x over previous
//
#include <hip/hip_runtime.h>
#include <hip/hip_bf16.h>

// Swin block: LN1+shift+window -> QKV GEMM -> [attention + proj + residual fused]
// -> LN2+MLP(GELU)+residual fused.  bf16 MFMA 16x16x32, f32 accum.
//
// R15: R14 (633us) + T5 s_setprio(1/0) around the MFMA clusters of the two
// latency-bound kernels (mlp_fused 361us, attn_proj 177us).  Both run 2
// INDEPENDENT blocks/CU (occupancy register-capped: ~116 arch VGPR + 96-128
// accum regs = 2 waves/SIMD; R10 proved forcing 3 spills acc) -> wave role
// diversity exists across blocks -> setprio arbitration applies (T5 regime).

typedef __attribute__((ext_vector_type(8))) short bf16x8;
typedef __attribute__((ext_vector_type(4))) float f32x4;

#define QSCALE 0.17677669529663687f

__device__ __forceinline__ unsigned short f2bf(float f) {
  union { float f; unsigned u; } v; v.f = f;
  unsigned r = v.u + 0x7fffu + ((v.u >> 16) & 1u);
  return (unsigned short)(r >> 16);
}

__device__ __forceinline__ float gelu_f(float h) {
  const float t0 = h * h;
  const float y2 = h * fmaf(-0.0713548163f, t0, -1.5957691216f);
  const float e = __expf(y2);
  return h / (1.f + e);
}

__device__ __forceinline__ void gload_lds16(const unsigned short* g, void* l) {
  __builtin_amdgcn_global_load_lds(
      (const __attribute__((address_space(1))) unsigned int*)g,
      (__attribute__((address_space(3))) unsigned int*)l, 16, 0, 0);
}

// ---------------- all weight transpose-converts in one launch (786432 elems)
__global__ __launch_bounds__(256) void wt_all(const float* __restrict__ qw,
                                              const float* __restrict__ kvw,
                                              const float* __restrict__ projw,
                                              const float* __restrict__ fc1w,
                                              const float* __restrict__ fc2w,
                                              unsigned short* __restrict__ dst) {
  const int e = blockIdx.x * 256 + threadIdx.x;
  float v;
  if (e < 65536) {                                  // qw (scaled)
    const int n = e >> 8, k = e & 255;
    v = qw[k * 256 + n] * QSCALE;
  } else if (e < 196608) {                          // kvw
    const int l = e - 65536, n = l >> 8, k = l & 255;
    v = kvw[k * 512 + n];
  } else if (e < 262144) {                          // projw
    const int l = e - 196608, n = l >> 8, k = l & 255;
    v = projw[k * 256 + n];
  } else if (e < 524288) {                          // fc1w
    const int l = e - 262144, n = l >> 8, k = l & 255;
    v = fc1w[k * 1024 + n];
  } else {                                          // fc2w
    const int l = e - 524288, n = l >> 10, k = l & 1023;
    v = fc2w[k * 256 + n];
  }
  dst[e] = f2bf(v);
}

// ---------------- fused rel-pos bias + shift mask table: T[4][8][64][64] f32
__global__ __launch_bounds__(256) void bias_tab(const float* __restrict__ rpb,
                                                float* __restrict__ tab) {
  const int e = blockIdx.x * 256 + threadIdx.x;     // 131072 total
  const int type = e >> 15, rem = e & 32767;
  const int h = rem >> 12, nm = rem & 4095, n = nm >> 6, m = nm & 63;
  const int ni = n >> 3, nj = n & 7, mi = m >> 3, mj = m & 7;
  const float bias = rpb[((ni - mi + 7) * 15 + (nj - mj + 7)) * 8 + h];
  const int twi = type >> 1, twj = type & 1;
  const int rn = twi ? (ni < 4 ? 1 : 2) : 0;
  const int cn = twj ? (nj < 4 ? 1 : 2) : 0;
  const int rm_ = twi ? (mi < 4 ? 1 : 2) : 0;
  const int cm_ = twj ? (mj < 4 ? 1 : 2) : 0;
  tab[e] = bias + (((rn * 3 + cn) != (rm_ * 3 + cm_)) ? -100.f : 0.f);
}

// ---------------- LN1 + cyclic shift + window partition. One wave per token.
__global__ __launch_bounds__(256) void ln1_win(const float* __restrict__ x,
                                               const float* __restrict__ g,
                                               const float* __restrict__ b,
                                               unsigned short* __restrict__ hw) {
  const int wv = threadIdx.x >> 6, ln = threadIdx.x & 63;
  const int r = blockIdx.x * 4 + wv;           // window-order token
  const int bw = r >> 6, n = r & 63;
  const int bb = bw >> 8, wi = (bw >> 4) & 15, wj = bw & 15;
  const int sh = (wi * 8 + (n >> 3) + 4) & 127;
  const int sw = (wj * 8 + (n & 7) + 4) & 127;
  const long src = ((long)bb * 16384 + sh * 128 + sw) * 256;
  float4 v = *(const float4*)(x + src + ln * 4);
  float s = v.x + v.y + v.z + v.w;
  float q = v.x * v.x + v.y * v.y + v.z * v.z + v.w * v.w;
#pragma unroll
  for (int m = 1; m < 64; m <<= 1) { s += __shfl_xor(s, m); q += __shfl_xor(q, m); }
  const float mu = s * (1.f / 256.f);
  const float rstd = rsqrtf(q * (1.f / 256.f) - mu * mu + 1e-5f);
  const int c = ln * 4;
  ushort4 o;
  o.x = f2bf((v.x - mu) * rstd * g[c + 0] + b[c + 0]);
  o.y = f2bf((v.y - mu) * rstd * g[c + 1] + b[c + 1]);
  o.z = f2bf((v.z - mu) * rstd * g[c + 2] + b[c + 2]);
  o.w = f2bf((v.w - mu) * rstd * g[c + 3] + b[c + 3]);
  *(ushort4*)(hw + (long)r * 256 + c) = o;
}

// ---------------- QKV GEMM: [M=131072][K=256] x [N=768] -> qkv bf16  [R12]
__global__ __launch_bounds__(256) void gemm_qkv(const unsigned short* __restrict__ A,
                                                const unsigned short* __restrict__ Bt,
                                                const float* __restrict__ qb,
                                                const float* __restrict__ kvb,
                                                unsigned short* __restrict__ out) {
  __shared__ char lds[32768];
  char* la = lds; char* lb = lds + 16384;
  const int tid = threadIdx.x, wv = tid >> 6, ln = tid & 63;
  const int lid = blockIdx.y * 6 + blockIdx.x;     // linear dispatch id
  const int r8 = lid & 7, k6 = lid >> 3;           // XCD, 0..767
  const int tm = r8 * 128 + k6 / 6;                // 0..1023
  const int tn = k6 - 6 * (k6 / 6);                // 0..5
  const long a_base = (long)tm * 128 * 256;
  const long b_base = (long)tn * 128 * 256;
  const int wr = (wv >> 1) * 64, wc = (wv & 1) * 64;
  f32x4 acc[4][4] = {};
  for (int ks = 0; ks < 4; ++ks) {
    const int k0 = ks * 64;
    __syncthreads();
#pragma unroll
    for (int it = 0; it < 4; ++it) {
      int d = wv * 4096 + it * 1024 + ln * 16;
      int row = d >> 7;
      int seg = ((d >> 4) & 7) ^ (row & 7);        // pre-swizzled source (m173)
      gload_lds16(A + a_base + row * 256 + k0 + seg * 8, la + wv * 4096 + it * 1024);
      gload_lds16(Bt + b_base + row * 256 + k0 + seg * 8, lb + wv * 4096 + it * 1024);
    }
    __syncthreads();
#pragma unroll
    for (int kk = 0; kk < 2; ++kk) {
      bf16x8 af[4], bfr[4];
      const int kb = (kk * 32 + (ln >> 4) * 8) * 2;
#pragma unroll
      for (int i = 0; i < 4; ++i) {
        int ra = wr + i * 16 + (ln & 15);
        af[i] = *(const bf16x8*)(la + ra * 128 + (kb ^ ((ra & 7) << 4)));
        int rb = wc + i * 16 + (ln & 15);
        bfr[i] = *(const bf16x8*)(lb + rb * 128 + (kb ^ ((rb & 7) << 4)));
      }
#pragma unroll
      for (int i = 0; i < 4; ++i)
#pragma unroll
        for (int j = 0; j < 4; ++j)
          acc[i][j] = __builtin_amdgcn_mfma_f32_16x16x32_bf16(af[i], bfr[j], acc[i][j], 0, 0, 0);
    }
  }
#pragma unroll
  for (int j = 0; j < 4; ++j) {
    const int col = tn * 128 + wc + j * 16 + (ln & 15);
    const float bias = (col < 256) ? qb[col] * QSCALE : kvb[col - 256];
#pragma unroll
    for (int i = 0; i < 4; ++i) {
      const int r0 = tm * 128 + wr + i * 16 + (ln >> 4) * 4;
#pragma unroll
      for (int rg = 0; rg < 4; ++rg)
        out[(long)(r0 + rg) * 768 + col] = f2bf(acc[i][j][rg] + bias);
    }
  }
}

// ---------------- fused attention + proj + window-reverse + residual  [R14+T5]
__global__ __launch_bounds__(256, 2) void attn_proj(const unsigned short* __restrict__ qkv,
                                                    const float* __restrict__ tab,
                                                    const unsigned short* __restrict__ wp,
                                                    const float* __restrict__ pb,
                                                    const float* __restrict__ x,
                                                    float* __restrict__ x1) {
  __shared__ char lds[49152];
  const int tid = threadIdx.x, wv = tid >> 6, ln = tid & 63;
  const int bw = blockIdx.x;                 // window 0..2047
  char* vt = lds + wv * 12288;               // [32][64] u16, XOR swizzled (4KB)
  char* pl = vt + 4096;                      // [64][64] bf16, XOR swizzled (8KB)
  const long base = (long)bw * 64 * 768;
  const int wi = (bw >> 4) & 15, wj = bw & 15;
  const int type = ((wi == 15) ? 2 : 0) | ((wj == 15) ? 1 : 0);
  f32x4 oo[2][4][2];
#pragma unroll
  for (int hh = 0; hh < 2; ++hh) {
    const int h = wv * 2 + hh;
    // stage this head's V (32 cols) transposed into vt (wave-private, no barrier)
#pragma unroll
    for (int it = 0; it < 4; ++it) {
      bf16x8 v = *(const bf16x8*)(qkv + base + (long)ln * 768 + 512 + h * 32 + it * 8);
#pragma unroll
      for (int u = 0; u < 8; ++u) {
        const int d = it * 8 + u;
        *(unsigned short*)(vt + ((d * 128 + 2 * ln) ^ ((d & 7) << 4))) = (unsigned short)v[u];
      }
    }
    const float* Tb = tab + (((type << 3) + h) << 12) + (ln & 15);
    f32x4 s[4][4] = {};
    {
      bf16x8 qf[4], kf[4];
      const int dk = (ln >> 4) * 8;
#pragma unroll
      for (int i = 0; i < 4; ++i) {
        const long rq = base + (long)(i * 16 + (ln & 15)) * 768;
        qf[i] = *(const bf16x8*)(qkv + rq + h * 32 + dk);
        kf[i] = *(const bf16x8*)(qkv + rq + 256 + h * 32 + dk);
      }
      __builtin_amdgcn_s_setprio(1);
#pragma unroll
      for (int i = 0; i < 4; ++i)
#pragma unroll
        for (int j = 0; j < 4; ++j)
          s[i][j] = __builtin_amdgcn_mfma_f32_16x16x32_bf16(qf[i], kf[j], s[i][j], 0, 0, 0);
      __builtin_amdgcn_s_setprio(0);
    }
#pragma unroll
    for (int i = 0; i < 4; ++i)
#pragma unroll
      for (int rg = 0; rg < 4; ++rg) {
        const int n = i * 16 + (ln >> 4) * 4 + rg;
        const float* Tn = Tb + n * 64;
#pragma unroll
        for (int j = 0; j < 4; ++j)
          s[i][j][rg] += Tn[j * 16];
      }
#pragma unroll
    for (int i = 0; i < 4; ++i)
#pragma unroll
      for (int rg = 0; rg < 4; ++rg) {
        float mx = fmaxf(fmaxf(s[i][0][rg], s[i][1][rg]), fmaxf(s[i][2][rg], s[i][3][rg]));
        mx = fmaxf(mx, __shfl_xor(mx, 1));
        mx = fmaxf(mx, __shfl_xor(mx, 2));
        mx = fmaxf(mx, __shfl_xor(mx, 4));
        mx = fmaxf(mx, __shfl_xor(mx, 8));
        float sum = 0.f;
#pragma unroll
        for (int j = 0; j < 4; ++j) { float e = __expf(s[i][j][rg] - mx); s[i][j][rg] = e; sum += e; }
        sum += __shfl_xor(sum, 1);
        sum += __shfl_xor(sum, 2);
        sum += __shfl_xor(sum, 4);
        sum += __shfl_xor(sum, 8);
        const float inv = 1.f / sum;
#pragma unroll
        for (int j = 0; j < 4; ++j) s[i][j][rg] *= inv;
      }
#pragma unroll
    for (int i = 0; i < 4; ++i)
#pragma unroll
      for (int rg = 0; rg < 4; ++rg) {
        const int n = i * 16 + (ln >> 4) * 4 + rg;
#pragma unroll
        for (int j = 0; j < 4; ++j) {
          const int m = j * 16 + (ln & 15);
          *(unsigned short*)(pl + n * 128 + ((m * 2) ^ ((n & 7) << 4))) = f2bf(s[i][j][rg]);
        }
      }
#pragma unroll
    for (int i = 0; i < 4; ++i)
#pragma unroll
      for (int j = 0; j < 2; ++j) oo[hh][i][j] = (f32x4){0.f, 0.f, 0.f, 0.f};
#pragma unroll
    for (int kk = 0; kk < 2; ++kk) {
      const int km = kk * 32 + (ln >> 4) * 8;
      bf16x8 pa[4], vb[2];
#pragma unroll
      for (int i = 0; i < 4; ++i) {
        const int n = i * 16 + (ln & 15);
        pa[i] = *(const bf16x8*)(pl + n * 128 + ((km * 2) ^ ((n & 7) << 4)));
      }
#pragma unroll
      for (int j = 0; j < 2; ++j) {
        const int r = j * 16 + (ln & 15);            // d within head (0..31)
        vb[j] = *(const bf16x8*)(vt + ((r * 128 + km * 2) ^ ((r & 7) << 4)));
      }
      __builtin_amdgcn_s_setprio(1);
#pragma unroll
      for (int i = 0; i < 4; ++i)
#pragma unroll
        for (int j = 0; j < 2; ++j)
          oo[hh][i][j] = __builtin_amdgcn_mfma_f32_16x16x32_bf16(pa[i], vb[j], oo[hh][i][j], 0, 0, 0);
      __builtin_amdgcn_s_setprio(0);
    }
  }
  __syncthreads();                 // all waves done with vt/pl
  // ---- O [64][256] bf16 swizzled into lds[0..32767]
#pragma unroll
  for (int hh = 0; hh < 2; ++hh)
#pragma unroll
    for (int i = 0; i < 4; ++i)
#pragma unroll
      for (int j = 0; j < 2; ++j)
#pragma unroll
        for (int rg = 0; rg < 4; ++rg) {
          const int t = i * 16 + (ln >> 4) * 4 + rg;
          const int c = wv * 64 + hh * 32 + j * 16 + (ln & 15);
          *(unsigned short*)(lds + t * 512 + ((c * 2) ^ ((t & 7) << 4))) = f2bf(oo[hh][i][j][rg]);
        }
  __syncthreads();                 // O ready
  f32x4 acc[4][4] = {};
#pragma unroll
  for (int kk = 0; kk < 8; ++kk) {
    bf16x8 af[4], bfr[4];
    const int kb = (kk * 32 + (ln >> 4) * 8) * 2;
#pragma unroll
    for (int i = 0; i < 4; ++i) {
      const int ra = i * 16 + (ln & 15);
      af[i] = *(const bf16x8*)(lds + ra * 512 + (kb ^ ((ra & 7) << 4)));
    }
#pragma unroll
    for (int j = 0; j < 4; ++j)
      bfr[j] = *(const bf16x8*)(wp + (long)(wv * 64 + j * 16 + (ln & 15)) * 256 +
                                kk * 32 + (ln >> 4) * 8);
    __builtin_amdgcn_s_setprio(1);
#pragma unroll
    for (int i = 0; i < 4; ++i)
#pragma unroll
      for (int j = 0; j < 4; ++j)
        acc[i][j] = __builtin_amdgcn_mfma_f32_16x16x32_bf16(af[i], bfr[j], acc[i][j], 0, 0, 0);
    __builtin_amdgcn_s_setprio(0);
  }
  const int bb = bw >> 8;
#pragma unroll
  for (int i = 0; i < 4; ++i)
#pragma unroll
    for (int rg = 0; rg < 4; ++rg) {
      const int n = i * 16 + (ln >> 4) * 4 + rg;
      const int sh = (wi * 8 + (n >> 3) + 4) & 127;
      const int sw = (wj * 8 + (n & 7) + 4) & 127;
      const long dst = ((long)bb * 16384 + sh * 128 + sw) * 256;
#pragma unroll
      for (int j = 0; j < 4; ++j) {
        const int col = wv * 64 + j * 16 + (ln & 15);
        x1[dst + col] = x[dst + col] + acc[i][j][rg] + pb[col];
      }
    }
}

// ---------------- fused LN2 + fc1 + GELU + fc2 + residual (f32 out)  [R9+T5]
__global__ __launch_bounds__(256, 2) void mlp_fused(const float* __restrict__ x1,
                                                    const float* __restrict__ g2,
                                                    const float* __restrict__ b2,
                                                    const unsigned short* __restrict__ w1t,
                                                    const float* __restrict__ fb1,
                                                    const unsigned short* __restrict__ w2t,
                                                    const float* __restrict__ fb2,
                                                    float* __restrict__ out) {
  __shared__ char lds[65536];           // A_ln 32KB | H0 16KB | H1 16KB
  char* h0 = lds + 32768;
  char* h1 = lds + 49152;
  const int tid = threadIdx.x, wv = tid >> 6, ln = tid & 63;
  const long rbase = (long)blockIdx.x * 64;
  {
    const int t = tid >> 2, q = tid & 3;
    const float* xr = x1 + (rbase + t) * 256 + q * 64;
    float4 v[16];
    float s = 0.f, sq = 0.f;
#pragma unroll
    for (int u = 0; u < 16; ++u) {
      v[u] = *(const float4*)(xr + u * 4);
      s += v[u].x + v[u].y + v[u].z + v[u].w;
      sq += v[u].x * v[u].x + v[u].y * v[u].y + v[u].z * v[u].z + v[u].w * v[u].w;
    }
    s += __shfl_xor(s, 1); s += __shfl_xor(s, 2);
    sq += __shfl_xor(sq, 1); sq += __shfl_xor(sq, 2);
    const float mu = s * (1.f / 256.f);
    const float rstd = rsqrtf(sq * (1.f / 256.f) - mu * mu + 1e-5f);
#pragma unroll
    for (int c8 = 0; c8 < 8; ++c8) {
      bf16x8 o;
#pragma unroll
      for (int u = 0; u < 8; ++u) {
        const int col = q * 64 + c8 * 8 + u;
        const float fv = ((&v[c8 * 2 + (u >> 2)].x)[u & 3] - mu) * rstd * g2[col] + b2[col];
        o[u] = (short)f2bf(fv);
      }
      *(bf16x8*)(lds + t * 512 + (((q * 64 + c8 * 8) * 2) ^ ((t & 7) << 4))) = o;
    }
  }

  f32x4 acc[4][4] = {};
  f32x4 hc[4][2];

  auto fc1_compute = [&](int ch) {
#pragma unroll
    for (int i = 0; i < 4; ++i)
#pragma unroll
      for (int j = 0; j < 2; ++j) hc[i][j] = (f32x4){0.f, 0.f, 0.f, 0.f};
#pragma unroll
    for (int ks = 0; ks < 8; ++ks) {
      bf16x8 af[4], wf[2];
#pragma unroll
      for (int j = 0; j < 2; ++j)
        wf[j] = *(const bf16x8*)(w1t + (long)(ch * 128 + wv * 32 + j * 16 + (ln & 15)) * 256 +
                                 ks * 32 + (ln >> 4) * 8);
      const int kb = (ks * 32 + (ln >> 4) * 8) * 2;
#pragma unroll
      for (int i = 0; i < 4; ++i) {
        const int ra = i * 16 + (ln & 15);
        af[i] = *(const bf16x8*)(lds + ra * 512 + (kb ^ ((ra & 7) << 4)));
      }
      __builtin_amdgcn_s_setprio(1);
#pragma unroll
      for (int i = 0; i < 4; ++i)
#pragma unroll
        for (int j = 0; j < 2; ++j)
          hc[i][j] = __builtin_amdgcn_mfma_f32_16x16x32_bf16(af[i], wf[j], hc[i][j], 0, 0, 0);
      __builtin_amdgcn_s_setprio(0);
    }
  };

  auto gelu_store = [&](int ch, char* hdst) {
#pragma unroll
    for (int j = 0; j < 2; ++j) {
      const int cH = wv * 32 + j * 16 + (ln & 15);
      const float fb = fb1[ch * 128 + cH];
#pragma unroll
      for (int i = 0; i < 4; ++i)
#pragma unroll
        for (int rg = 0; rg < 4; ++rg) {
          const int t = i * 16 + (ln >> 4) * 4 + rg;
          const float val = hc[i][j][rg] + fb;
          *(unsigned short*)(hdst + t * 256 + ((cH * 2) ^ ((t & 7) << 4))) = f2bf(gelu_f(val));
        }
    }
  };

  auto fc2_compute = [&](int ch, const char* hsrc) {
#pragma unroll
    for (int kk = 0; kk < 4; ++kk) {
      const int kb2 = kk * 32 + (ln >> 4) * 8;
      bf16x8 ha[4], wb[4];
#pragma unroll
      for (int j = 0; j < 4; ++j)
        wb[j] = *(const bf16x8*)(w2t + (long)(wv * 64 + j * 16 + (ln & 15)) * 1024 +
                                 ch * 128 + kb2);
#pragma unroll
      for (int i = 0; i < 4; ++i) {
        const int tt = i * 16 + (ln & 15);
        ha[i] = *(const bf16x8*)(hsrc + tt * 256 + ((kb2 * 2) ^ ((tt & 7) << 4)));
      }
      __builtin_amdgcn_s_setprio(1);
#pragma unroll
      for (int i = 0; i < 4; ++i)
#pragma unroll
        for (int j = 0; j < 4; ++j)
          acc[i][j] = __builtin_amdgcn_mfma_f32_16x16x32_bf16(ha[i], wb[j], acc[i][j], 0, 0, 0);
      __builtin_amdgcn_s_setprio(0);
    }
  };

  __syncthreads();              // A_ln ready
  fc1_compute(0);
  gelu_store(0, h0);
  __syncthreads();              // H0 ready
#pragma unroll 2
  for (int ch = 0; ch < 8; ++ch) {
    char* hr = (ch & 1) ? h1 : h0;
    char* hw2 = (ch & 1) ? h0 : h1;
    if (ch < 7) fc1_compute(ch + 1);   // indep chain: W1 global + A LDS
    fc2_compute(ch, hr);               // indep chain: H LDS + W2 global
    if (ch < 7) {
      gelu_store(ch + 1, hw2);
      __syncthreads();                 // H[(ch+1)&1] ready; H[ch&1] free
    }
  }
#pragma unroll
  for (int i = 0; i < 4; ++i)
#pragma unroll
    for (int rg = 0; rg < 4; ++rg) {
      const long t = rbase + i * 16 + (ln >> 4) * 4 + rg;
#pragma unroll
      for (int j = 0; j < 4; ++j) {
        const int col = wv * 64 + j * 16 + (ln & 15);
        out[t * 256 + col] = x1[t * 256 + col] + acc[i][j][rg] + fb2[col];
      }
    }
}

extern "C" void kernel_launch(void* const* d_in, const int* in_sizes, int n_in,
                              void* d_out, int out_size, void* d_ws, size_t ws_size,
                              hipStream_t stream) {
  const float* x     = (const float*)d_in[0];
  const float* g1    = (const float*)d_in[1];
  const float* b1    = (const float*)d_in[2];
  const float* qw    = (const float*)d_in[3];
  const float* qb    = (const float*)d_in[4];
  const float* kvw   = (const float*)d_in[5];
  const float* kvb   = (const float*)d_in[6];
  const float* rpb   = (const float*)d_in[7];
  const float* projw = (const float*)d_in[8];
  const float* projb = (const float*)d_in[9];
  const float* g2    = (const float*)d_in[10];
  const float* b2    = (const float*)d_in[11];
  const float* fc1w  = (const float*)d_in[12];
  const float* fc1b  = (const float*)d_in[13];
  const float* fc2w  = (const float*)d_in[14];
  const float* fc2b  = (const float*)d_in[15];

  // Workspace: weights bf16 | qkv bf16 | tab f32   (~203.4 MB)
  unsigned short* wqkv  = (unsigned short*)d_ws;            // 196608
  unsigned short* wproj = wqkv + 196608;                     // 65536
  unsigned short* wfc1  = wproj + 65536;                     // 262144
  unsigned short* wfc2  = wfc1 + 262144;                     // 262144
  unsigned short* qkv   = wfc2 + 262144;                     // 100663296
  float* tab = (float*)(qkv + 100663296);                    // 131072 f32
  // d_out f32: ln1's hw bf16 scratch in first half (dead after gemm_qkv);
  // attn_proj writes x1 f32 over d_out; mlp_fused rewrites in place.
  unsigned short* hw = (unsigned short*)d_out;
  float* x1 = (float*)d_out;

  wt_all<<<3072, 256, 0, stream>>>(qw, kvw, projw, fc1w, fc2w, wqkv);
  bias_tab<<<512, 256, 0, stream>>>(rpb, tab);

  ln1_win<<<32768, 256, 0, stream>>>(x, g1, b1, hw);
  gemm_qkv<<<dim3(6, 1024), 256, 0, stream>>>(hw, wqkv, qb, kvb, qkv);
  attn_proj<<<2048, 256, 0, stream>>>(qkv, tab, wproj, projb, x, x1);
  mlp_fused<<<2048, 256, 0, stream>>>(x1, g2, b2, wfc1, fc1b, wfc2, fc2b,
                                      (float*)d_out);
}